// Round 5
// baseline (172.648 us; speedup 1.0000x reference)
//
#include <hip/hip_runtime.h>
#include <hip/hip_bf16.h>

typedef __attribute__((ext_vector_type(8))) short short8;
typedef __attribute__((ext_vector_type(4))) float f32x4;
typedef unsigned short us;

#define B_ 2
#define S_ 2048
#define D_ 1024
#define H_ 16
#define DK_ 64
#define QSCALE 0.1803368867f  // log2(e) / 8

__device__ __forceinline__ us f2bf(float f) {
  union { float f; unsigned u; } x; x.f = f;
  unsigned r = x.u + 0x7FFFu + ((x.u >> 16) & 1u);
  return (us)(r >> 16);
}
__device__ __forceinline__ float bf2f(us h) {
  union { unsigned u; float f; } x; x.u = ((unsigned)h) << 16;
  return x.f;
}
__device__ __forceinline__ us f2bf_hw(float f) {
  __hip_bfloat16 h = __float2bfloat16(f);
  return *reinterpret_cast<us*>(&h);
}

__device__ __forceinline__ void gload16(const void* g, void* l) {
  __builtin_amdgcn_global_load_lds((const __attribute__((address_space(1))) void*)g,
                                   (__attribute__((address_space(3))) void*)l, 16, 0, 0);
}

__global__ __launch_bounds__(256) void cvt3_kernel(const float* __restrict__ a,
                                                   const float* __restrict__ b,
                                                   const float* __restrict__ c,
                                                   us* __restrict__ oa,
                                                   us* __restrict__ ob,
                                                   us* __restrict__ oc) {
  const float* in; us* out;
  if (blockIdx.y == 0) { in = a; out = oa; }
  else if (blockIdx.y == 1) { in = b; out = ob; }
  else { in = c; out = oc; }
  int i = (blockIdx.x * 256 + threadIdx.x) * 4;
  float4 v = *reinterpret_cast<const float4*>(in + i);
  ushort4 o;
  o.x = f2bf(v.x); o.y = f2bf(v.y); o.z = f2bf(v.z); o.w = f2bf(v.w);
  *reinterpret_cast<ushort4*>(out + i) = o;
}

__global__ __launch_bounds__(256) void cvt4_kernel(const float* __restrict__ a,
                                                   const float* __restrict__ b,
                                                   const float* __restrict__ c,
                                                   const float* __restrict__ d,
                                                   us* __restrict__ oa, us* __restrict__ ob,
                                                   us* __restrict__ oc, us* __restrict__ od) {
  const float* in; us* out;
  if (blockIdx.y == 0) { in = a; out = oa; }
  else if (blockIdx.y == 1) { in = b; out = ob; }
  else if (blockIdx.y == 2) { in = c; out = oc; }
  else { in = d; out = od; }
  int i = (blockIdx.x * 256 + threadIdx.x) * 4;
  float4 v = *reinterpret_cast<const float4*>(in + i);
  ushort4 o;
  o.x = f2bf(v.x); o.y = f2bf(v.y); o.z = f2bf(v.z); o.w = f2bf(v.w);
  *reinterpret_cast<ushort4*>(out + i) = o;
}

__global__ __launch_bounds__(256) void rs_kernel(const float* __restrict__ reaches,
                                                 float* __restrict__ rs) {
  int b = blockIdx.x, t = threadIdx.x;
  float s = 0.f;
  for (int i = t; i < S_; i += 256) s += reaches[b * S_ + i];
  for (int o = 32; o > 0; o >>= 1) s += __shfl_down(s, o, 64);
  __shared__ float tmp[4];
  if ((t & 63) == 0) tmp[t >> 6] = s;
  __syncthreads();
  if (t == 0) rs[b] = tmp[0] + tmp[1] + tmp[2] + tmp[3];
}

// m97-structure GEMM: 128x128 tile, BK=32, linear LDS + global_load_lds w16.
// M=4096, N=1024, K=1024, A row-major, Bt row-major (B^T). bf16 head-split out.
__device__ __forceinline__ void gemm_core_hs(const us* __restrict__ A, const us* __restrict__ Bt,
                                             us* __restrict__ outH, float oscale) {
  __shared__ __align__(16) us lA[128 * 32];
  __shared__ __align__(16) us lB[128 * 32];
  const int tid = threadIdx.x;
  const int bm = blockIdx.x >> 3, bn = blockIdx.x & 7;
  const int w = tid >> 6, lane = tid & 63;
  const int wr = (w >> 1) * 64, wc = (w & 1) * 64;
  const int lr = lane & 15, lg = lane >> 4;

  f32x4 acc[4][4];
#pragma unroll
  for (int i = 0; i < 4; ++i)
#pragma unroll
    for (int j = 0; j < 4; ++j) acc[i][j] = (f32x4){0.f, 0.f, 0.f, 0.f};

  const int crow = lane >> 2, ce8 = (lane & 3) * 8;
  const us* A0 = A + (size_t)(bm * 128 + w * 32 + crow) * 1024 + ce8;
  const us* A1 = A0 + (size_t)16 * 1024;
  const us* B0 = Bt + (size_t)(bn * 128 + w * 32 + crow) * 1024 + ce8;
  const us* B1 = B0 + (size_t)16 * 1024;
  us* lA0 = &lA[(w * 2) * 512]; us* lA1 = lA0 + 512;
  us* lB0 = &lB[(w * 2) * 512]; us* lB1 = lB0 + 512;

  for (int kt = 0; kt < 1024; kt += 32) {
    gload16(A0 + kt, lA0);
    gload16(A1 + kt, lA1);
    gload16(B0 + kt, lB0);
    gload16(B1 + kt, lB1);
    __syncthreads();
    short8 af[4], bfr[4];
#pragma unroll
    for (int i = 0; i < 4; ++i)
      af[i] = *reinterpret_cast<const short8*>(&lA[(wr + i * 16 + lr) * 32 + lg * 8]);
#pragma unroll
    for (int j = 0; j < 4; ++j)
      bfr[j] = *reinterpret_cast<const short8*>(&lB[(wc + j * 16 + lr) * 32 + lg * 8]);
#pragma unroll
    for (int i = 0; i < 4; ++i)
#pragma unroll
      for (int j = 0; j < 4; ++j)
        acc[i][j] = __builtin_amdgcn_mfma_f32_16x16x32_bf16(af[i], bfr[j], acc[i][j], 0, 0, 0);
    __syncthreads();
  }
#pragma unroll
  for (int i = 0; i < 4; ++i)
#pragma unroll
    for (int j = 0; j < 4; ++j)
#pragma unroll
      for (int ii = 0; ii < 4; ++ii) {
        int r = bm * 128 + wr + i * 16 + lg * 4 + ii;
        int c = bn * 128 + wc + j * 16 + lr;
        float v = acc[i][j][ii] * oscale;
        int b = r >> 11, s = r & (S_ - 1), h = c >> 6, dk = c & 63;
        outH[(((size_t)(b * H_ + h) * S_ + s) * DK_) + dk] = f2bf(v);
      }
}

__global__ __launch_bounds__(256) void proj_gemm(const us* __restrict__ q_bf,
                                                 const us* __restrict__ k_bf,
                                                 const us* __restrict__ v_bf,
                                                 const us* __restrict__ Wq_bf,
                                                 const us* __restrict__ Wk_bf,
                                                 const us* __restrict__ Wv_bf,
                                                 us* __restrict__ Qh, us* __restrict__ Kh,
                                                 us* __restrict__ Vh) {
  if (blockIdx.y == 0) gemm_core_hs(q_bf, Wq_bf, Qh, QSCALE);
  else if (blockIdx.y == 1) gemm_core_hs(k_bf, Wk_bf, Kh, 1.0f);
  else gemm_core_hs(v_bf, Wv_bf, Vh, 1.0f);
}

// Wo GEMM: 128x64 tile (grid 512 = 2 blocks/CU), fp32 output.
__global__ __launch_bounds__(256) void wo_gemm(const us* __restrict__ A,
                                               const us* __restrict__ Bt,
                                               float* __restrict__ outF) {
  __shared__ __align__(16) us lA[128 * 32];
  __shared__ __align__(16) us lB[64 * 32];
  const int tid = threadIdx.x;
  const int bm = blockIdx.x >> 4, bn = blockIdx.x & 15;
  const int w = tid >> 6, lane = tid & 63;
  const int lr = lane & 15, lg = lane >> 4;

  f32x4 acc[2][4];
#pragma unroll
  for (int i = 0; i < 2; ++i)
#pragma unroll
    for (int j = 0; j < 4; ++j) acc[i][j] = (f32x4){0.f, 0.f, 0.f, 0.f};

  const int crow = lane >> 2, ce8 = (lane & 3) * 8;
  const us* A0 = A + (size_t)(bm * 128 + w * 32 + crow) * 1024 + ce8;
  const us* A1 = A0 + (size_t)16 * 1024;
  const us* B0 = Bt + (size_t)(bn * 64 + w * 16 + crow) * 1024 + ce8;
  us* lA0 = &lA[w * 1024]; us* lA1 = lA0 + 512;
  us* lB0 = &lB[w * 512];

  for (int kt = 0; kt < 1024; kt += 32) {
    gload16(A0 + kt, lA0);
    gload16(A1 + kt, lA1);
    gload16(B0 + kt, lB0);
    __syncthreads();
    short8 af[2], bfr[4];
#pragma unroll
    for (int i = 0; i < 2; ++i)
      af[i] = *reinterpret_cast<const short8*>(&lA[(w * 32 + i * 16 + lr) * 32 + lg * 8]);
#pragma unroll
    for (int j = 0; j < 4; ++j)
      bfr[j] = *reinterpret_cast<const short8*>(&lB[(j * 16 + lr) * 32 + lg * 8]);
#pragma unroll
    for (int i = 0; i < 2; ++i)
#pragma unroll
      for (int j = 0; j < 4; ++j)
        acc[i][j] = __builtin_amdgcn_mfma_f32_16x16x32_bf16(af[i], bfr[j], acc[i][j], 0, 0, 0);
    __syncthreads();
  }
#pragma unroll
  for (int i = 0; i < 2; ++i)
#pragma unroll
    for (int j = 0; j < 4; ++j)
#pragma unroll
      for (int ii = 0; ii < 4; ++ii) {
        int r = bm * 128 + w * 32 + i * 16 + lg * 4 + ii;
        int c = bn * 64 + j * 16 + lr;
        outF[(size_t)r * 1024 + c] = acc[i][j][ii];
      }
}

// Vh [B,H,S,DK] -> VhT [B,H,DK,S]
__global__ __launch_bounds__(256) void transp_kernel(const us* __restrict__ Vh,
                                                     us* __restrict__ VhT) {
  __shared__ us t[64 * 68];
  const int bh = blockIdx.x >> 5, st = blockIdx.x & 31;
  const size_t base = (size_t)bh * S_ * DK_;
  const int r = threadIdx.x >> 3, e8 = (threadIdx.x & 7) * 8;
#pragma unroll
  for (int h2 = 0; h2 < 2; ++h2) {
    int row = r + h2 * 32;
    *reinterpret_cast<short8*>(&t[row * 68 + e8]) =
        *reinterpret_cast<const short8*>(&Vh[base + (size_t)(st * 64 + row) * DK_ + e8]);
  }
  __syncthreads();
#pragma unroll
  for (int h2 = 0; h2 < 2; ++h2) {
    int dk = (threadIdx.x >> 3) + h2 * 32;
    int sc = (threadIdx.x & 7) * 8;
    short8 v;
#pragma unroll
    for (int j = 0; j < 8; ++j) v[j] = t[(sc + j) * 68 + dk];
    *reinterpret_cast<short8*>(&VhT[base + (size_t)dk * S_ + st * 64 + sc]) = v;
  }
}

// Quadrant-split streaming-softmax attention.
// 4 waves = 2x2: wq = q-half (32 rows), wk = k-half (32 cols). Q in registers.
__global__ __launch_bounds__(256, 4) void attn_kernel(const us* __restrict__ Qh,
                                                      const us* __restrict__ Kh,
                                                      const us* __restrict__ Vh,
                                                      const us* __restrict__ VhT,
                                                      const float* __restrict__ reaches,
                                                      const float* __restrict__ rsum,
                                                      us* __restrict__ concat) {
  __shared__ __align__(16) us smem[14080];  // lK [64][72] | vT [64][72] | pw [64][76]
  __shared__ float lscr[64];
  us* lK = smem;
  us* vT = smem + 4608;
  us* pw = smem + 9216;
  float* fscr = reinterpret_cast<float*>(smem);  // epilogue reuse (16 KB)

  const int tid = threadIdx.x;
  const int bid = ((blockIdx.x & 7) << 7) | (blockIdx.x >> 3);  // XCD-chunked swizzle
  const int qt = bid & 31;
  const int bh = bid >> 5;
  const int b = bh >> 4, h = bh & 15;
  const size_t base = (size_t)bh * S_ * DK_;

  const int w = tid >> 6, lane = tid & 63;
  const int wq = w >> 1, wk = w & 1;
  const int lr = lane & 15, lg = lane >> 4;
  const int r2 = tid >> 3, e8 = (tid & 7) * 8;

  // Q fragments in registers (per-wave q-half, pre-scaled by log2e/8)
  short8 aq[2][2];
#pragma unroll
  for (int i = 0; i < 2; ++i)
#pragma unroll
    for (int kk = 0; kk < 2; ++kk)
      aq[i][kk] = *reinterpret_cast<const short8*>(
          &Qh[base + (size_t)(qt * 64 + wq * 32 + i * 16 + lr) * DK_ + kk * 32 + lg * 8]);

  // stage tile 0 (T14 pattern: reg prefetch, LDS write, barrier)
  short8 pk0, pk1, pv0, pv1;
  pk0 = *reinterpret_cast<const short8*>(&Kh[base + (size_t)r2 * DK_ + e8]);
  pk1 = *reinterpret_cast<const short8*>(&Kh[base + (size_t)(r2 + 32) * DK_ + e8]);
  pv0 = *reinterpret_cast<const short8*>(&VhT[base + (size_t)r2 * S_ + e8]);
  pv1 = *reinterpret_cast<const short8*>(&VhT[base + (size_t)(r2 + 32) * S_ + e8]);
  *reinterpret_cast<short8*>(&lK[r2 * 72 + e8]) = pk0;
  *reinterpret_cast<short8*>(&lK[(r2 + 32) * 72 + e8]) = pk1;
  *reinterpret_cast<short8*>(&vT[r2 * 72 + e8]) = pv0;
  *reinterpret_cast<short8*>(&vT[(r2 + 32) * 72 + e8]) = pv1;
  __syncthreads();

  f32x4 acc[2][4];
  float lacc[2][4];
#pragma unroll
  for (int i = 0; i < 2; ++i) {
#pragma unroll
    for (int c4 = 0; c4 < 4; ++c4) acc[i][c4] = (f32x4){0.f, 0.f, 0.f, 0.f};
#pragma unroll
    for (int ii = 0; ii < 4; ++ii) lacc[i][ii] = 0.f;
  }

  for (int kt = 0; kt < 32; ++kt) {
    if (kt < 31) {
      int nt = kt + 1;
      pk0 = *reinterpret_cast<const short8*>(&Kh[base + (size_t)(nt * 64 + r2) * DK_ + e8]);
      pk1 = *reinterpret_cast<const short8*>(&Kh[base + (size_t)(nt * 64 + r2 + 32) * DK_ + e8]);
      pv0 = *reinterpret_cast<const short8*>(&VhT[base + (size_t)r2 * S_ + nt * 64 + e8]);
      pv1 = *reinterpret_cast<const short8*>(&VhT[base + (size_t)(r2 + 32) * S_ + nt * 64 + e8]);
    }
    float rwc[2];
#pragma unroll
    for (int j = 0; j < 2; ++j)
      rwc[j] = reaches[b * S_ + kt * 64 + wk * 32 + j * 16 + lr];

    // QK^T quadrant: sf[i][j] covers q rows [32wq+16i, +16) x k cols [32wk+16j, +16)
    f32x4 sf[2][2];
#pragma unroll
    for (int i = 0; i < 2; ++i)
#pragma unroll
      for (int j = 0; j < 2; ++j) sf[i][j] = (f32x4){0.f, 0.f, 0.f, 0.f};
#pragma unroll
    for (int kk = 0; kk < 2; ++kk) {
      short8 bb[2];
#pragma unroll
      for (int j = 0; j < 2; ++j)
        bb[j] = *reinterpret_cast<const short8*>(
            &lK[(wk * 32 + j * 16 + lr) * 72 + kk * 32 + lg * 8]);
#pragma unroll
      for (int i = 0; i < 2; ++i)
#pragma unroll
        for (int j = 0; j < 2; ++j)
          sf[i][j] = __builtin_amdgcn_mfma_f32_16x16x32_bf16(aq[i][kk], bb[j], sf[i][j], 0, 0, 0);
    }

    // streaming softmax: P = 2^S', accumulate partial l, weight, write quadrant of pw
    if (kt == qt) {
#pragma unroll
      for (int i = 0; i < 2; ++i)
#pragma unroll
        for (int j = 0; j < 2; ++j) {
          int kloc = wk * 32 + j * 16 + lr;
#pragma unroll
          for (int ii = 0; ii < 4; ++ii) {
            float e = __builtin_amdgcn_exp2f(sf[i][j][ii]);
            lacc[i][ii] += e;
            float wg = rwc[j];
            if (kloc == wq * 32 + i * 16 + lg * 4 + ii) wg *= (1.0f - 0.999999f);
            pw[(wq * 32 + i * 16 + lg * 4 + ii) * 76 + kloc] = f2bf_hw(e * wg);
          }
        }
    } else {
#pragma unroll
      for (int i = 0; i < 2; ++i)
#pragma unroll
        for (int j = 0; j < 2; ++j) {
          int kloc = wk * 32 + j * 16 + lr;
#pragma unroll
          for (int ii = 0; ii < 4; ++ii) {
            float e = __builtin_amdgcn_exp2f(sf[i][j][ii]);
            lacc[i][ii] += e;
            pw[(wq * 32 + i * 16 + lg * 4 + ii) * 76 + kloc] = f2bf_hw(e * rwc[j]);
          }
        }
    }

    // PV over this wave's k-half (pw quadrant wave-private; no barrier needed)
    short8 pa[2];
#pragma unroll
    for (int i = 0; i < 2; ++i)
      pa[i] = *reinterpret_cast<const short8*>(
          &pw[(wq * 32 + i * 16 + lr) * 76 + wk * 32 + lg * 8]);
#pragma unroll
    for (int c4 = 0; c4 < 4; ++c4) {
      short8 bb = *reinterpret_cast<const short8*>(
          &vT[(c4 * 16 + lr) * 72 + wk * 32 + lg * 8]);
#pragma unroll
      for (int i = 0; i < 2; ++i)
        acc[i][c4] = __builtin_amdgcn_mfma_f32_16x16x32_bf16(pa[i], bb, acc[i][c4], 0, 0, 0);
    }
    __syncthreads();
    if (kt < 31) {
      *reinterpret_cast<short8*>(&lK[r2 * 72 + e8]) = pk0;
      *reinterpret_cast<short8*>(&lK[(r2 + 32) * 72 + e8]) = pk1;
      *reinterpret_cast<short8*>(&vT[r2 * 72 + e8]) = pv0;
      *reinterpret_cast<short8*>(&vT[(r2 + 32) * 72 + e8]) = pv1;
    }
    __syncthreads();
  }

  // reduce lacc across the 16-lane lr group (sum over this wave's k-half)
#pragma unroll
  for (int o = 1; o <= 8; o <<= 1)
#pragma unroll
    for (int i = 0; i < 2; ++i)
#pragma unroll
      for (int ii = 0; ii < 4; ++ii) lacc[i][ii] += __shfl_xor(lacc[i][ii], o, 64);

  // cross-wave merge: wk=1 waves dump partial O and l, wk=0 waves combine + write
  if (wk == 1) {
#pragma unroll
    for (int i = 0; i < 2; ++i)
#pragma unroll
      for (int c4 = 0; c4 < 4; ++c4)
#pragma unroll
        for (int ii = 0; ii < 4; ++ii)
          fscr[(wq * 32 + i * 16 + lg * 4 + ii) * 64 + c4 * 16 + lr] = acc[i][c4][ii];
    if (lr == 0)
#pragma unroll
      for (int i = 0; i < 2; ++i)
#pragma unroll
        for (int ii = 0; ii < 4; ++ii) lscr[wq * 32 + i * 16 + lg * 4 + ii] = lacc[i][ii];
  }
  __syncthreads();
  if (wk == 0) {
    const float rb = rsum[b];
#pragma unroll
    for (int i = 0; i < 2; ++i)
#pragma unroll
      for (int ii = 0; ii < 4; ++ii) {
        int qloc = wq * 32 + i * 16 + lg * 4 + ii;
        int qg = qt * 64 + qloc;
        float ltot = lacc[i][ii] + lscr[qloc];
        float rq = reaches[b * S_ + qg];
        float contrib = (rb - rq) / (rb + 1e-9f) * (1.f - rq) * 100.f;
#pragma unroll
        for (int c4 = 0; c4 < 4; ++c4) {
          int d = c4 * 16 + lr;
          float pv = (acc[i][c4][ii] + fscr[qloc * 64 + d]) / ltot;
          float vhv = bf2f(Vh[base + (size_t)qg * DK_ + d]);
          float o = (vhv - pv) * contrib;
          concat[((size_t)(b * S_ + qg)) * D_ + h * 64 + d] = f2bf(o);
        }
      }
  }
}

extern "C" void kernel_launch(void* const* d_in, const int* in_sizes, int n_in,
                              void* d_out, int out_size, void* d_ws, size_t ws_size,
                              hipStream_t stream) {
  const float* q = (const float*)d_in[0];
  const float* k = (const float*)d_in[1];
  const float* v = (const float*)d_in[2];
  const float* reaches = (const float*)d_in[3];
  const float* Wq = (const float*)d_in[4];
  const float* Wk = (const float*)d_in[5];
  const float* Wv = (const float*)d_in[6];
  const float* Wo = (const float*)d_in[7];

  const size_t NQKV = (size_t)B_ * S_ * D_;
  const size_t NW = (size_t)D_ * D_;

  us* q_bf = (us*)d_ws;
  us* k_bf = q_bf + NQKV;
  us* v_bf = k_bf + NQKV;
  us* Wq_bf = v_bf + NQKV;
  us* Wk_bf = Wq_bf + NW;
  us* Wv_bf = Wk_bf + NW;
  us* Wo_bf = Wv_bf + NW;
  us* Qh = Wo_bf + NW;
  us* Kh = Qh + NQKV;
  us* Vh = Kh + NQKV;
  us* concat = Vh + NQKV;
  float* rs = (float*)(concat + NQKV);
  us* VhT = q_bf;  // alias: q_bf dead after proj_gemm

  cvt3_kernel<<<dim3(NQKV / 1024, 3), 256, 0, stream>>>(q, k, v, q_bf, k_bf, v_bf);
  cvt4_kernel<<<dim3(NW / 1024, 4), 256, 0, stream>>>(Wq, Wk, Wv, Wo, Wq_bf, Wk_bf, Wv_bf, Wo_bf);
  rs_kernel<<<B_, 256, 0, stream>>>(reaches, rs);

  proj_gemm<<<dim3(256, 3), 256, 0, stream>>>(q_bf, k_bf, v_bf, Wq_bf, Wk_bf, Wv_bf, Qh, Kh, Vh);
  transp_kernel<<<B_ * H_ * (S_ / 64), 256, 0, stream>>>(Vh, VhT);

  attn_kernel<<<B_ * H_ * (S_ / 64), 256, 0, stream>>>(Qh, Kh, Vh, VhT, reaches, rs, concat);

  wo_gemm<<<512, 256, 0, stream>>>(concat, Wo_bf, (float*)d_out);
}

// Round 6
// 163.891 us; speedup vs baseline: 1.0534x; 1.0534x over previous
//
#include <hip/hip_runtime.h>
#include <hip/hip_bf16.h>

typedef __attribute__((ext_vector_type(8))) short short8;
typedef __attribute__((ext_vector_type(4))) float f32x4;
typedef unsigned short us;

#define B_ 2
#define S_ 2048
#define D_ 1024
#define H_ 16
#define DK_ 64
#define QSCALE 0.1803368867f  // log2(e) / 8

__device__ __forceinline__ us f2bf(float f) {
  union { float f; unsigned u; } x; x.f = f;
  unsigned r = x.u + 0x7FFFu + ((x.u >> 16) & 1u);
  return (us)(r >> 16);
}
__device__ __forceinline__ float bf2f(us h) {
  union { unsigned u; float f; } x; x.u = ((unsigned)h) << 16;
  return x.f;
}
__device__ __forceinline__ us f2bf_hw(float f) {
  __hip_bfloat16 h = __float2bfloat16(f);
  return *reinterpret_cast<us*>(&h);
}

__device__ __forceinline__ void gload16(const void* g, void* l) {
  __builtin_amdgcn_global_load_lds((const __attribute__((address_space(1))) void*)g,
                                   (__attribute__((address_space(3))) void*)l, 16, 0, 0);
}

// One kernel for all 7 fp32->bf16 conversions (saves launch gaps).
__global__ __launch_bounds__(256) void cvt_all(const float* __restrict__ q,
                                               const float* __restrict__ k,
                                               const float* __restrict__ v,
                                               const float* __restrict__ Wq,
                                               const float* __restrict__ Wk,
                                               const float* __restrict__ Wv,
                                               const float* __restrict__ Wo,
                                               us* __restrict__ oq, us* __restrict__ ok,
                                               us* __restrict__ ov, us* __restrict__ oWq,
                                               us* __restrict__ oWk, us* __restrict__ oWv,
                                               us* __restrict__ oWo) {
  int bid = blockIdx.x;
  const float* in; us* out; int off;
  if (bid < 12288) {
    int t = bid >> 12;
    in = (t == 0) ? q : (t == 1) ? k : v;
    out = (t == 0) ? oq : (t == 1) ? ok : ov;
    off = (bid & 4095) * 1024;
  } else {
    int t = (bid - 12288) >> 10;
    in = (t == 0) ? Wq : (t == 1) ? Wk : (t == 2) ? Wv : Wo;
    out = (t == 0) ? oWq : (t == 1) ? oWk : (t == 2) ? oWv : oWo;
    off = ((bid - 12288) & 1023) * 1024;
  }
  int i = off + threadIdx.x * 4;
  float4 val = *reinterpret_cast<const float4*>(in + i);
  ushort4 o;
  o.x = f2bf(val.x); o.y = f2bf(val.y); o.z = f2bf(val.z); o.w = f2bf(val.w);
  *reinterpret_cast<ushort4*>(out + i) = o;
}

__global__ __launch_bounds__(256) void rs_kernel(const float* __restrict__ reaches,
                                                 float* __restrict__ rs) {
  int b = blockIdx.x, t = threadIdx.x;
  float s = 0.f;
  for (int i = t; i < S_; i += 256) s += reaches[b * S_ + i];
  for (int o = 32; o > 0; o >>= 1) s += __shfl_down(s, o, 64);
  __shared__ float tmp[4];
  if ((t & 63) == 0) tmp[t >> 6] = s;
  __syncthreads();
  if (t == 0) rs[b] = tmp[0] + tmp[1] + tmp[2] + tmp[3];
}

// m97-structure GEMM: 128x128 tile, BK=32, linear LDS + global_load_lds w16.
// M=4096, N=1024, K=1024, A row-major, Bt row-major (B^T). bf16 head-split out.
__device__ __forceinline__ void gemm_core_hs(const us* __restrict__ A, const us* __restrict__ Bt,
                                             us* __restrict__ outH, float oscale) {
  __shared__ __align__(16) us lA[128 * 32];
  __shared__ __align__(16) us lB[128 * 32];
  const int tid = threadIdx.x;
  const int bm = blockIdx.x >> 3, bn = blockIdx.x & 7;
  const int w = tid >> 6, lane = tid & 63;
  const int wr = (w >> 1) * 64, wc = (w & 1) * 64;
  const int lr = lane & 15, lg = lane >> 4;

  f32x4 acc[4][4];
#pragma unroll
  for (int i = 0; i < 4; ++i)
#pragma unroll
    for (int j = 0; j < 4; ++j) acc[i][j] = (f32x4){0.f, 0.f, 0.f, 0.f};

  const int crow = lane >> 2, ce8 = (lane & 3) * 8;
  const us* A0 = A + (size_t)(bm * 128 + w * 32 + crow) * 1024 + ce8;
  const us* A1 = A0 + (size_t)16 * 1024;
  const us* B0 = Bt + (size_t)(bn * 128 + w * 32 + crow) * 1024 + ce8;
  const us* B1 = B0 + (size_t)16 * 1024;
  us* lA0 = &lA[(w * 2) * 512]; us* lA1 = lA0 + 512;
  us* lB0 = &lB[(w * 2) * 512]; us* lB1 = lB0 + 512;

  for (int kt = 0; kt < 1024; kt += 32) {
    gload16(A0 + kt, lA0);
    gload16(A1 + kt, lA1);
    gload16(B0 + kt, lB0);
    gload16(B1 + kt, lB1);
    __syncthreads();
    short8 af[4], bfr[4];
#pragma unroll
    for (int i = 0; i < 4; ++i)
      af[i] = *reinterpret_cast<const short8*>(&lA[(wr + i * 16 + lr) * 32 + lg * 8]);
#pragma unroll
    for (int j = 0; j < 4; ++j)
      bfr[j] = *reinterpret_cast<const short8*>(&lB[(wc + j * 16 + lr) * 32 + lg * 8]);
#pragma unroll
    for (int i = 0; i < 4; ++i)
#pragma unroll
      for (int j = 0; j < 4; ++j)
        acc[i][j] = __builtin_amdgcn_mfma_f32_16x16x32_bf16(af[i], bfr[j], acc[i][j], 0, 0, 0);
    __syncthreads();
  }
#pragma unroll
  for (int i = 0; i < 4; ++i)
#pragma unroll
    for (int j = 0; j < 4; ++j)
#pragma unroll
      for (int ii = 0; ii < 4; ++ii) {
        int r = bm * 128 + wr + i * 16 + lg * 4 + ii;
        int c = bn * 128 + wc + j * 16 + lr;
        float v = acc[i][j][ii] * oscale;
        int b = r >> 11, s = r & (S_ - 1), h = c >> 6, dk = c & 63;
        outH[(((size_t)(b * H_ + h) * S_ + s) * DK_) + dk] = f2bf(v);
      }
}

__global__ __launch_bounds__(256) void proj_gemm(const us* __restrict__ q_bf,
                                                 const us* __restrict__ k_bf,
                                                 const us* __restrict__ v_bf,
                                                 const us* __restrict__ Wq_bf,
                                                 const us* __restrict__ Wk_bf,
                                                 const us* __restrict__ Wv_bf,
                                                 us* __restrict__ Qh, us* __restrict__ Kh,
                                                 us* __restrict__ Vh) {
  if (blockIdx.y == 0) gemm_core_hs(q_bf, Wq_bf, Qh, QSCALE);
  else if (blockIdx.y == 1) gemm_core_hs(k_bf, Wk_bf, Kh, 1.0f);
  else gemm_core_hs(v_bf, Wv_bf, Vh, 1.0f);
}

// Wo GEMM: 128x64 tile (grid 512 = 2 blocks/CU), fp32 output.
__global__ __launch_bounds__(256) void wo_gemm(const us* __restrict__ A,
                                               const us* __restrict__ Bt,
                                               float* __restrict__ outF) {
  __shared__ __align__(16) us lA[128 * 32];
  __shared__ __align__(16) us lB[64 * 32];
  const int tid = threadIdx.x;
  const int bm = blockIdx.x >> 4, bn = blockIdx.x & 15;
  const int w = tid >> 6, lane = tid & 63;
  const int lr = lane & 15, lg = lane >> 4;

  f32x4 acc[2][4];
#pragma unroll
  for (int i = 0; i < 2; ++i)
#pragma unroll
    for (int j = 0; j < 4; ++j) acc[i][j] = (f32x4){0.f, 0.f, 0.f, 0.f};

  const int crow = lane >> 2, ce8 = (lane & 3) * 8;
  const us* A0 = A + (size_t)(bm * 128 + w * 32 + crow) * 1024 + ce8;
  const us* A1 = A0 + (size_t)16 * 1024;
  const us* B0 = Bt + (size_t)(bn * 64 + w * 16 + crow) * 1024 + ce8;
  us* lA0 = &lA[w * 1024]; us* lA1 = lA0 + 512;
  us* lB0 = &lB[w * 512];

  for (int kt = 0; kt < 1024; kt += 32) {
    gload16(A0 + kt, lA0);
    gload16(A1 + kt, lA1);
    gload16(B0 + kt, lB0);
    __syncthreads();
    short8 af[2], bfr[4];
#pragma unroll
    for (int i = 0; i < 2; ++i)
      af[i] = *reinterpret_cast<const short8*>(&lA[(w * 32 + i * 16 + lr) * 32 + lg * 8]);
#pragma unroll
    for (int j = 0; j < 4; ++j)
      bfr[j] = *reinterpret_cast<const short8*>(&lB[(j * 16 + lr) * 32 + lg * 8]);
#pragma unroll
    for (int i = 0; i < 2; ++i)
#pragma unroll
      for (int j = 0; j < 4; ++j)
        acc[i][j] = __builtin_amdgcn_mfma_f32_16x16x32_bf16(af[i], bfr[j], acc[i][j], 0, 0, 0);
    __syncthreads();
  }
#pragma unroll
  for (int i = 0; i < 2; ++i)
#pragma unroll
    for (int j = 0; j < 4; ++j)
#pragma unroll
      for (int ii = 0; ii < 4; ++ii) {
        int r = bm * 128 + w * 32 + i * 16 + lg * 4 + ii;
        int c = bn * 64 + j * 16 + lr;
        outF[(size_t)r * 1024 + c] = acc[i][j][ii];
      }
}

// Vh [B,H,S,DK] -> VhT [B,H,DK,S]
__global__ __launch_bounds__(256) void transp_kernel(const us* __restrict__ Vh,
                                                     us* __restrict__ VhT) {
  __shared__ us t[64 * 68];
  const int bh = blockIdx.x >> 5, st = blockIdx.x & 31;
  const size_t base = (size_t)bh * S_ * DK_;
  const int r = threadIdx.x >> 3, e8 = (threadIdx.x & 7) * 8;
#pragma unroll
  for (int h2 = 0; h2 < 2; ++h2) {
    int row = r + h2 * 32;
    *reinterpret_cast<short8*>(&t[row * 68 + e8]) =
        *reinterpret_cast<const short8*>(&Vh[base + (size_t)(st * 64 + row) * DK_ + e8]);
  }
  __syncthreads();
#pragma unroll
  for (int h2 = 0; h2 < 2; ++h2) {
    int dk = (threadIdx.x >> 3) + h2 * 32;
    int sc = (threadIdx.x & 7) * 8;
    short8 v;
#pragma unroll
    for (int j = 0; j < 8; ++j) v[j] = t[(sc + j) * 68 + dk];
    *reinterpret_cast<short8*>(&VhT[base + (size_t)dk * S_ + st * 64 + sc]) = v;
  }
}

// Row-split streaming-softmax attention, double-buffered K/V: ONE barrier per kt.
// Wave w owns q rows [16w, 16w+16); Q in registers. Q pre-scaled by log2(e)/8.
__global__ __launch_bounds__(256, 3) void attn_kernel(const us* __restrict__ Qh,
                                                      const us* __restrict__ Kh,
                                                      const us* __restrict__ Vh,
                                                      const us* __restrict__ VhT,
                                                      const float* __restrict__ reaches,
                                                      const float* __restrict__ rsum,
                                                      us* __restrict__ concat) {
  __shared__ __align__(16) us lK2[2][64 * 72];
  __shared__ __align__(16) us vT2[2][64 * 72];
  __shared__ __align__(16) us pw[64 * 76];

  const int tid = threadIdx.x;
  const int bid = ((blockIdx.x & 7) << 7) | (blockIdx.x >> 3);  // XCD-chunked swizzle
  const int qt = bid & 31;
  const int bh = bid >> 5;
  const int b = bh >> 4, h = bh & 15;
  const size_t base = (size_t)bh * S_ * DK_;

  const int w = tid >> 6, lane = tid & 63;
  const int lr = lane & 15, lg = lane >> 4;
  const int r2 = tid >> 3, e8 = (tid & 7) * 8;

  // Q fragments in registers (wave-private 16 rows)
  short8 aq[2];
#pragma unroll
  for (int kk = 0; kk < 2; ++kk)
    aq[kk] = *reinterpret_cast<const short8*>(
        &Qh[base + (size_t)(qt * 64 + w * 16 + lr) * DK_ + kk * 32 + lg * 8]);

  // prologue: stage tile 0 into buffer 0
  short8 pk0, pk1, pv0, pv1;
  pk0 = *reinterpret_cast<const short8*>(&Kh[base + (size_t)r2 * DK_ + e8]);
  pk1 = *reinterpret_cast<const short8*>(&Kh[base + (size_t)(r2 + 32) * DK_ + e8]);
  pv0 = *reinterpret_cast<const short8*>(&VhT[base + (size_t)r2 * S_ + e8]);
  pv1 = *reinterpret_cast<const short8*>(&VhT[base + (size_t)(r2 + 32) * S_ + e8]);
  *reinterpret_cast<short8*>(&lK2[0][r2 * 72 + e8]) = pk0;
  *reinterpret_cast<short8*>(&lK2[0][(r2 + 32) * 72 + e8]) = pk1;
  *reinterpret_cast<short8*>(&vT2[0][r2 * 72 + e8]) = pv0;
  *reinterpret_cast<short8*>(&vT2[0][(r2 + 32) * 72 + e8]) = pv1;
  __syncthreads();

  const int qg0 = qt * 64 + w * 16 + lg * 4;  // q row of acc reg ii = qg0+ii
  f32x4 acc[4];
  float lacc[4] = {0.f, 0.f, 0.f, 0.f};
#pragma unroll
  for (int c4 = 0; c4 < 4; ++c4) acc[c4] = (f32x4){0.f, 0.f, 0.f, 0.f};

  for (int kt = 0; kt < 32; ++kt) {
    const int cur = kt & 1;
    if (kt < 31) {  // prefetch next tile into regs (hides HBM/L2 latency under compute)
      int nt = kt + 1;
      pk0 = *reinterpret_cast<const short8*>(&Kh[base + (size_t)(nt * 64 + r2) * DK_ + e8]);
      pk1 = *reinterpret_cast<const short8*>(&Kh[base + (size_t)(nt * 64 + r2 + 32) * DK_ + e8]);
      pv0 = *reinterpret_cast<const short8*>(&VhT[base + (size_t)r2 * S_ + nt * 64 + e8]);
      pv1 = *reinterpret_cast<const short8*>(&VhT[base + (size_t)(r2 + 32) * S_ + nt * 64 + e8]);
    }
    float rwc[4];
#pragma unroll
    for (int c4 = 0; c4 < 4; ++c4) rwc[c4] = reaches[b * S_ + kt * 64 + c4 * 16 + lr];

    // S' = Q K^T (scale folded into Q); C-layout row q = w*16+lg*4+ii, col k = c4*16+lr
    f32x4 sf[4];
#pragma unroll
    for (int c4 = 0; c4 < 4; ++c4) sf[c4] = (f32x4){0.f, 0.f, 0.f, 0.f};
#pragma unroll
    for (int kk = 0; kk < 2; ++kk) {
#pragma unroll
      for (int c4 = 0; c4 < 4; ++c4) {
        short8 bb = *reinterpret_cast<const short8*>(
            &lK2[cur][(c4 * 16 + lr) * 72 + kk * 32 + lg * 8]);
        sf[c4] = __builtin_amdgcn_mfma_f32_16x16x32_bf16(aq[kk], bb, sf[c4], 0, 0, 0);
      }
    }

    // streaming (max-free) softmax: P = 2^S', partial l, reach weight, diag suppress
    if (kt == qt) {
#pragma unroll
      for (int c4 = 0; c4 < 4; ++c4) {
#pragma unroll
        for (int ii = 0; ii < 4; ++ii) {
          float e = __builtin_amdgcn_exp2f(sf[c4][ii]);
          lacc[ii] += e;
          float wg = rwc[c4];
          if (c4 * 16 + lr == w * 16 + lg * 4 + ii) wg *= (1.0f - 0.999999f);
          pw[(w * 16 + lg * 4 + ii) * 76 + c4 * 16 + lr] = f2bf_hw(e * wg);
        }
      }
    } else {
#pragma unroll
      for (int c4 = 0; c4 < 4; ++c4) {
#pragma unroll
        for (int ii = 0; ii < 4; ++ii) {
          float e = __builtin_amdgcn_exp2f(sf[c4][ii]);
          lacc[ii] += e;
          pw[(w * 16 + lg * 4 + ii) * 76 + c4 * 16 + lr] = f2bf_hw(e * rwc[c4]);
        }
      }
    }

    // PV: acc += pw @ V  (pw rows wave-private; in-wave lgkm deps only)
#pragma unroll
    for (int kk = 0; kk < 2; ++kk) {
      short8 pa = *reinterpret_cast<const short8*>(&pw[(w * 16 + lr) * 76 + kk * 32 + lg * 8]);
#pragma unroll
      for (int c4 = 0; c4 < 4; ++c4) {
        short8 bb = *reinterpret_cast<const short8*>(
            &vT2[cur][(c4 * 16 + lr) * 72 + kk * 32 + lg * 8]);
        acc[c4] = __builtin_amdgcn_mfma_f32_16x16x32_bf16(pa, bb, acc[c4], 0, 0, 0);
      }
    }

    // stage next tile into the other buffer; single barrier orders everything:
    //  - these writes vs next-iter readers
    //  - next-iter's writes (to buf cur) vs this-iter readers of cur
    if (kt < 31) {
      const int nx = cur ^ 1;
      *reinterpret_cast<short8*>(&lK2[nx][r2 * 72 + e8]) = pk0;
      *reinterpret_cast<short8*>(&lK2[nx][(r2 + 32) * 72 + e8]) = pk1;
      *reinterpret_cast<short8*>(&vT2[nx][r2 * 72 + e8]) = pv0;
      *reinterpret_cast<short8*>(&vT2[nx][(r2 + 32) * 72 + e8]) = pv1;
    }
    __syncthreads();
  }

  // deferred l reduction across the 16-lane lr group
#pragma unroll
  for (int o = 1; o <= 8; o <<= 1)
#pragma unroll
    for (int ii = 0; ii < 4; ++ii) lacc[ii] += __shfl_xor(lacc[ii], o, 64);

  const float rb = rsum[b];
  float contrib[4];
#pragma unroll
  for (int ii = 0; ii < 4; ++ii) {
    float rq = reaches[b * S_ + qg0 + ii];
    contrib[ii] = (rb - rq) / (rb + 1e-9f) * (1.f - rq) * 100.f;
  }
#pragma unroll
  for (int c4 = 0; c4 < 4; ++c4)
#pragma unroll
    for (int ii = 0; ii < 4; ++ii) {
      int qg = qg0 + ii;
      int d = c4 * 16 + lr;
      float pv = acc[c4][ii] / lacc[ii];
      float vhv = bf2f(Vh[base + (size_t)qg * DK_ + d]);
      float o = (vhv - pv) * contrib[ii];
      concat[((size_t)(b * S_ + qg)) * D_ + h * 64 + d] = f2bf(o);
    }
}

extern "C" void kernel_launch(void* const* d_in, const int* in_sizes, int n_in,
                              void* d_out, int out_size, void* d_ws, size_t ws_size,
                              hipStream_t stream) {
  const float* q = (const float*)d_in[0];
  const float* k = (const float*)d_in[1];
  const float* v = (const float*)d_in[2];
  const float* reaches = (const float*)d_in[3];
  const float* Wq = (const float*)d_in[4];
  const float* Wk = (const float*)d_in[5];
  const float* Wv = (const float*)d_in[6];
  const float* Wo = (const float*)d_in[7];

  const size_t NQKV = (size_t)B_ * S_ * D_;
  const size_t NW = (size_t)D_ * D_;

  us* q_bf = (us*)d_ws;
  us* k_bf = q_bf + NQKV;
  us* v_bf = k_bf + NQKV;
  us* Wq_bf = v_bf + NQKV;
  us* Wk_bf = Wq_bf + NW;
  us* Wv_bf = Wk_bf + NW;
  us* Wo_bf = Wv_bf + NW;
  us* Qh = Wo_bf + NW;
  us* Kh = Qh + NQKV;
  us* Vh = Kh + NQKV;
  us* concat = Vh + NQKV;
  float* rs = (float*)(concat + NQKV);
  us* VhT = q_bf;  // alias: q_bf dead after proj_gemm

  cvt_all<<<16384, 256, 0, stream>>>(q, k, v, Wq, Wk, Wv, Wo,
                                     q_bf, k_bf, v_bf, Wq_bf, Wk_bf, Wv_bf, Wo_bf);
  rs_kernel<<<B_, 256, 0, stream>>>(reaches, rs);

  proj_gemm<<<dim3(256, 3), 256, 0, stream>>>(q_bf, k_bf, v_bf, Wq_bf, Wk_bf, Wv_bf, Qh, Kh, Vh);
  transp_kernel<<<B_ * H_ * (S_ / 64), 256, 0, stream>>>(Vh, VhT);

  attn_kernel<<<B_ * H_ * (S_ / 64), 256, 0, stream>>>(Qh, Kh, Vh, VhT, reaches, rs, concat);

  wo_gemm<<<512, 256, 0, stream>>>(concat, Wo_bf, (float*)d_out);
}

// Round 7
// 141.344 us; speedup vs baseline: 1.2215x; 1.1595x over previous
//
#include <hip/hip_runtime.h>
#include <hip/hip_bf16.h>

typedef __attribute__((ext_vector_type(8))) short short8;
typedef __attribute__((ext_vector_type(4))) float f32x4;
typedef __attribute__((ext_vector_type(16))) float f32x16;
typedef unsigned short us;

#define B_ 2
#define S_ 2048
#define D_ 1024
#define H_ 16
#define DK_ 64
#define QSCALE 0.1803368867f  // log2(e) / 8

__device__ __forceinline__ us f2bf(float f) {
  union { float f; unsigned u; } x; x.f = f;
  unsigned r = x.u + 0x7FFFu + ((x.u >> 16) & 1u);
  return (us)(r >> 16);
}
__device__ __forceinline__ float bf2f(us h) {
  union { unsigned u; float f; } x; x.u = ((unsigned)h) << 16;
  return x.f;
}
__device__ __forceinline__ us f2bf_hw(float f) {
  __hip_bfloat16 h = __float2bfloat16(f);
  return *reinterpret_cast<us*>(&h);
}

__device__ __forceinline__ void gload16(const void* g, void* l) {
  __builtin_amdgcn_global_load_lds((const __attribute__((address_space(1))) void*)g,
                                   (__attribute__((address_space(3))) void*)l, 16, 0, 0);
}

// One kernel for all 7 fp32->bf16 conversions.
__global__ __launch_bounds__(256) void cvt_all(const float* __restrict__ q,
                                               const float* __restrict__ k,
                                               const float* __restrict__ v,
                                               const float* __restrict__ Wq,
                                               const float* __restrict__ Wk,
                                               const float* __restrict__ Wv,
                                               const float* __restrict__ Wo,
                                               us* __restrict__ oq, us* __restrict__ ok,
                                               us* __restrict__ ov, us* __restrict__ oWq,
                                               us* __restrict__ oWk, us* __restrict__ oWv,
                                               us* __restrict__ oWo) {
  int bid = blockIdx.x;
  const float* in; us* out; int off;
  if (bid < 12288) {
    int t = bid >> 12;
    in = (t == 0) ? q : (t == 1) ? k : v;
    out = (t == 0) ? oq : (t == 1) ? ok : ov;
    off = (bid & 4095) * 1024;
  } else {
    int t = (bid - 12288) >> 10;
    in = (t == 0) ? Wq : (t == 1) ? Wk : (t == 2) ? Wv : Wo;
    out = (t == 0) ? oWq : (t == 1) ? oWk : (t == 2) ? oWv : oWo;
    off = ((bid - 12288) & 1023) * 1024;
  }
  int i = off + threadIdx.x * 4;
  float4 val = *reinterpret_cast<const float4*>(in + i);
  ushort4 o;
  o.x = f2bf(val.x); o.y = f2bf(val.y); o.z = f2bf(val.z); o.w = f2bf(val.w);
  *reinterpret_cast<ushort4*>(out + i) = o;
}

__global__ __launch_bounds__(256) void rs_kernel(const float* __restrict__ reaches,
                                                 float* __restrict__ rs) {
  int b = blockIdx.x, t = threadIdx.x;
  float s = 0.f;
  for (int i = t; i < S_; i += 256) s += reaches[b * S_ + i];
  for (int o = 32; o > 0; o >>= 1) s += __shfl_down(s, o, 64);
  __shared__ float tmp[4];
  if ((t & 63) == 0) tmp[t >> 6] = s;
  __syncthreads();
  if (t == 0) rs[b] = tmp[0] + tmp[1] + tmp[2] + tmp[3];
}

// m97-structure GEMM: 128x128 tile, BK=32, linear LDS + global_load_lds w16.
__device__ __forceinline__ void gemm_core_hs(const us* __restrict__ A, const us* __restrict__ Bt,
                                             us* __restrict__ outH, float oscale) {
  __shared__ __align__(16) us lA[128 * 32];
  __shared__ __align__(16) us lB[128 * 32];
  const int tid = threadIdx.x;
  const int bm = blockIdx.x >> 3, bn = blockIdx.x & 7;
  const int w = tid >> 6, lane = tid & 63;
  const int wr = (w >> 1) * 64, wc = (w & 1) * 64;
  const int lr = lane & 15, lg = lane >> 4;

  f32x4 acc[4][4];
#pragma unroll
  for (int i = 0; i < 4; ++i)
#pragma unroll
    for (int j = 0; j < 4; ++j) acc[i][j] = (f32x4){0.f, 0.f, 0.f, 0.f};

  const int crow = lane >> 2, ce8 = (lane & 3) * 8;
  const us* A0 = A + (size_t)(bm * 128 + w * 32 + crow) * 1024 + ce8;
  const us* A1 = A0 + (size_t)16 * 1024;
  const us* B0 = Bt + (size_t)(bn * 128 + w * 32 + crow) * 1024 + ce8;
  const us* B1 = B0 + (size_t)16 * 1024;
  us* lA0 = &lA[(w * 2) * 512]; us* lA1 = lA0 + 512;
  us* lB0 = &lB[(w * 2) * 512]; us* lB1 = lB0 + 512;

  for (int kt = 0; kt < 1024; kt += 32) {
    gload16(A0 + kt, lA0);
    gload16(A1 + kt, lA1);
    gload16(B0 + kt, lB0);
    gload16(B1 + kt, lB1);
    __syncthreads();
    short8 af[4], bfr[4];
#pragma unroll
    for (int i = 0; i < 4; ++i)
      af[i] = *reinterpret_cast<const short8*>(&lA[(wr + i * 16 + lr) * 32 + lg * 8]);
#pragma unroll
    for (int j = 0; j < 4; ++j)
      bfr[j] = *reinterpret_cast<const short8*>(&lB[(wc + j * 16 + lr) * 32 + lg * 8]);
#pragma unroll
    for (int i = 0; i < 4; ++i)
#pragma unroll
      for (int j = 0; j < 4; ++j)
        acc[i][j] = __builtin_amdgcn_mfma_f32_16x16x32_bf16(af[i], bfr[j], acc[i][j], 0, 0, 0);
    __syncthreads();
  }
#pragma unroll
  for (int i = 0; i < 4; ++i)
#pragma unroll
    for (int j = 0; j < 4; ++j)
#pragma unroll
      for (int ii = 0; ii < 4; ++ii) {
        int r = bm * 128 + wr + i * 16 + lg * 4 + ii;
        int c = bn * 128 + wc + j * 16 + lr;
        float v = acc[i][j][ii] * oscale;
        int b = r >> 11, s = r & (S_ - 1), h = c >> 6, dk = c & 63;
        outH[(((size_t)(b * H_ + h) * S_ + s) * DK_) + dk] = f2bf(v);
      }
}

__global__ __launch_bounds__(256) void proj_gemm(const us* __restrict__ q_bf,
                                                 const us* __restrict__ k_bf,
                                                 const us* __restrict__ v_bf,
                                                 const us* __restrict__ Wq_bf,
                                                 const us* __restrict__ Wk_bf,
                                                 const us* __restrict__ Wv_bf,
                                                 us* __restrict__ Qh, us* __restrict__ Kh,
                                                 us* __restrict__ Vh) {
  if (blockIdx.y == 0) gemm_core_hs(q_bf, Wq_bf, Qh, QSCALE);
  else if (blockIdx.y == 1) gemm_core_hs(k_bf, Wk_bf, Kh, 1.0f);
  else gemm_core_hs(v_bf, Wv_bf, Vh, 1.0f);
}

// Wo GEMM: 128x64 tile (grid 512 = 2 blocks/CU), fp32 output.
__global__ __launch_bounds__(256) void wo_gemm(const us* __restrict__ A,
                                               const us* __restrict__ Bt,
                                               float* __restrict__ outF) {
  __shared__ __align__(16) us lA[128 * 32];
  __shared__ __align__(16) us lB[64 * 32];
  const int tid = threadIdx.x;
  const int bm = blockIdx.x >> 4, bn = blockIdx.x & 15;
  const int w = tid >> 6, lane = tid & 63;
  const int lr = lane & 15, lg = lane >> 4;

  f32x4 acc[2][4];
#pragma unroll
  for (int i = 0; i < 2; ++i)
#pragma unroll
    for (int j = 0; j < 4; ++j) acc[i][j] = (f32x4){0.f, 0.f, 0.f, 0.f};

  const int crow = lane >> 2, ce8 = (lane & 3) * 8;
  const us* A0 = A + (size_t)(bm * 128 + w * 32 + crow) * 1024 + ce8;
  const us* A1 = A0 + (size_t)16 * 1024;
  const us* B0 = Bt + (size_t)(bn * 64 + w * 16 + crow) * 1024 + ce8;
  us* lA0 = &lA[w * 1024]; us* lA1 = lA0 + 512;
  us* lB0 = &lB[w * 512];

  for (int kt = 0; kt < 1024; kt += 32) {
    gload16(A0 + kt, lA0);
    gload16(A1 + kt, lA1);
    gload16(B0 + kt, lB0);
    __syncthreads();
    short8 af[2], bfr[4];
#pragma unroll
    for (int i = 0; i < 2; ++i)
      af[i] = *reinterpret_cast<const short8*>(&lA[(w * 32 + i * 16 + lr) * 32 + lg * 8]);
#pragma unroll
    for (int j = 0; j < 4; ++j)
      bfr[j] = *reinterpret_cast<const short8*>(&lB[(j * 16 + lr) * 32 + lg * 8]);
#pragma unroll
    for (int i = 0; i < 2; ++i)
#pragma unroll
      for (int j = 0; j < 4; ++j)
        acc[i][j] = __builtin_amdgcn_mfma_f32_16x16x32_bf16(af[i], bfr[j], acc[i][j], 0, 0, 0);
    __syncthreads();
  }
#pragma unroll
  for (int i = 0; i < 2; ++i)
#pragma unroll
    for (int j = 0; j < 4; ++j)
#pragma unroll
      for (int ii = 0; ii < 4; ++ii) {
        int r = bm * 128 + w * 32 + i * 16 + lg * 4 + ii;
        int c = bn * 64 + j * 16 + lr;
        outF[(size_t)r * 1024 + c] = acc[i][j][ii];
      }
}

// Vh [B,H,S,DK] -> VhTw [B,H,DK,S] with reach weighting folded in:
// VhTw[bh][d][s] = Vh[bh][s][d] * reaches[b][s]
__global__ __launch_bounds__(256) void transp_kernel(const us* __restrict__ Vh,
                                                     const float* __restrict__ reaches,
                                                     us* __restrict__ VhTw) {
  __shared__ us t[64 * 68];
  const int bh = blockIdx.x >> 5, st = blockIdx.x & 31;
  const int b = bh >> 4;
  const size_t base = (size_t)bh * S_ * DK_;
  const int r = threadIdx.x >> 3, e8 = (threadIdx.x & 7) * 8;
#pragma unroll
  for (int h2 = 0; h2 < 2; ++h2) {
    int row = r + h2 * 32;
    *reinterpret_cast<short8*>(&t[row * 68 + e8]) =
        *reinterpret_cast<const short8*>(&Vh[base + (size_t)(st * 64 + row) * DK_ + e8]);
  }
  __syncthreads();
#pragma unroll
  for (int h2 = 0; h2 < 2; ++h2) {
    int dk = (threadIdx.x >> 3) + h2 * 32;
    int sc = (threadIdx.x & 7) * 8;
    short8 v;
#pragma unroll
    for (int j = 0; j < 8; ++j) {
      float rw = reaches[b * S_ + st * 64 + sc + j];
      v[j] = (short)f2bf_hw(bf2f(t[(sc + j) * 68 + dk]) * rw);
    }
    *reinterpret_cast<short8*>(&VhTw[base + (size_t)dk * S_ + st * 64 + sc]) = v;
  }
}

// 32x32-MFMA streaming-softmax attention. 4 waves x 32 q-rows = 128-row q-tile.
// Q in regs; K/V' double-buffered in XOR-swizzled LDS [64][64]; one barrier/kt.
// reach folded into V'; diagonal suppression via epilogue rank-1 correction.
__global__ __launch_bounds__(256, 2) void attn_kernel(const us* __restrict__ Qh,
                                                      const us* __restrict__ Kh,
                                                      const us* __restrict__ Vh,
                                                      const us* __restrict__ VhTw,
                                                      const float* __restrict__ reaches,
                                                      const float* __restrict__ rsum,
                                                      us* __restrict__ concat) {
  __shared__ __align__(16) us lK2[2][64 * 64];
  __shared__ __align__(16) us vT2[2][64 * 64];
  __shared__ __align__(16) us pw[128 * 72];
  __shared__ float diagP[128];

  const int tid = threadIdx.x;
  const int bid = ((blockIdx.x & 7) << 6) | (blockIdx.x >> 3);  // XCD swizzle (512 = 8*64)
  const int qt = bid & 15;
  const int bh = bid >> 4;
  const int b = bh >> 4, h = bh & 15;
  const size_t base = (size_t)bh * S_ * DK_;  // same stride for [S,DK] and [DK,S]

  const int w = tid >> 6, lane = tid & 63;
  const int l31 = lane & 31, hh = lane >> 5, l7 = lane & 7;
  const int h4 = hh * 4;
  const int r2 = tid >> 3, e8 = (tid & 7) * 8;
  const int diagkt = qt * 2 + (w >> 1);

  // Q fragments in regs: aq[dk] = Q[q = qt*128 + w*32 + l31][d = dk*16 + hh*8 ..+8]
  short8 aq[4];
  {
    const us* qp = &Qh[base + (size_t)(qt * 128 + w * 32 + l31) * DK_ + hh * 8];
#pragma unroll
    for (int dk = 0; dk < 4; ++dk)
      aq[dk] = *reinterpret_cast<const short8*>(qp + dk * 16);
  }

  // loop-invariant LDS element offsets (XOR swizzle at 16B granularity)
  int rdK[2][4], rdV[2][4], rdP[4];
#pragma unroll
  for (int c = 0; c < 2; ++c)
#pragma unroll
    for (int dk = 0; dk < 4; ++dk) {
      rdK[c][dk] = (c * 32 + l31) * 64 + (((dk * 2 + hh) ^ l7) << 3);
      rdV[c][dk] = rdK[c][dk];  // same pattern (row=col-block + l31, slot=(ks*2+hh)^l7)
    }
#pragma unroll
  for (int ks = 0; ks < 4; ++ks) rdP[ks] = (w * 32 + l31) * 72 + ks * 16 + hh * 8;
  const int pwW = (w * 32 + h4) * 72 + l31;
  const int wslot = ((tid & 7) ^ (r2 & 7)) << 3;
  const int wK0 = r2 * 64 + wslot, wK1 = (r2 + 32) * 64 + wslot;

  // prologue: stage tile 0
  short8 pk0, pk1, pv0, pv1;
  pk0 = *reinterpret_cast<const short8*>(&Kh[base + (size_t)r2 * DK_ + e8]);
  pk1 = *reinterpret_cast<const short8*>(&Kh[base + (size_t)(r2 + 32) * DK_ + e8]);
  pv0 = *reinterpret_cast<const short8*>(&VhTw[base + (size_t)r2 * S_ + e8]);
  pv1 = *reinterpret_cast<const short8*>(&VhTw[base + (size_t)(r2 + 32) * S_ + e8]);
  *reinterpret_cast<short8*>(&lK2[0][wK0]) = pk0;
  *reinterpret_cast<short8*>(&lK2[0][wK1]) = pk1;
  *reinterpret_cast<short8*>(&vT2[0][wK0]) = pv0;
  *reinterpret_cast<short8*>(&vT2[0][wK1]) = pv1;
  __syncthreads();

  f32x16 oacc[2];
  float lacc[16];
#pragma unroll
  for (int c = 0; c < 2; ++c)
#pragma unroll
    for (int r = 0; r < 16; ++r) oacc[c][r] = 0.f;
#pragma unroll
  for (int r = 0; r < 16; ++r) lacc[r] = 0.f;

  for (int kt = 0; kt < 32; ++kt) {
    const int cur = kt & 1;
    if (kt < 31) {
      int nt = kt + 1;
      pk0 = *reinterpret_cast<const short8*>(&Kh[base + (size_t)(nt * 64 + r2) * DK_ + e8]);
      pk1 = *reinterpret_cast<const short8*>(&Kh[base + (size_t)(nt * 64 + r2 + 32) * DK_ + e8]);
      pv0 = *reinterpret_cast<const short8*>(&VhTw[base + (size_t)r2 * S_ + nt * 64 + e8]);
      pv1 = *reinterpret_cast<const short8*>(&VhTw[base + (size_t)(r2 + 32) * S_ + nt * 64 + e8]);
    }

    // QK^T: S[q 32][k 64] in two 32-col blocks
    f32x16 sf0, sf1;
#pragma unroll
    for (int r = 0; r < 16; ++r) { sf0[r] = 0.f; sf1[r] = 0.f; }
    __builtin_amdgcn_s_setprio(1);
#pragma unroll
    for (int dk = 0; dk < 4; ++dk) {
      short8 b0 = *reinterpret_cast<const short8*>(&lK2[cur][rdK[0][dk]]);
      sf0 = __builtin_amdgcn_mfma_f32_32x32x16_bf16(aq[dk], b0, sf0, 0, 0, 0);
      short8 b1 = *reinterpret_cast<const short8*>(&lK2[cur][rdK[1][dk]]);
      sf1 = __builtin_amdgcn_mfma_f32_32x32x16_bf16(aq[dk], b1, sf1, 0, 0, 0);
    }
    __builtin_amdgcn_s_setprio(0);

    // streaming softmax: e = 2^s, lacc += e, pw = bf16(e)
#pragma unroll
    for (int r = 0; r < 16; ++r) {
      const int rowc = (r & 3) + 8 * (r >> 2);
      float e0 = __builtin_amdgcn_exp2f(sf0[r]);
      float e1 = __builtin_amdgcn_exp2f(sf1[r]);
      lacc[r] += e0 + e1;
      pw[pwW + rowc * 72] = f2bf_hw(e0);
      pw[pwW + rowc * 72 + 32] = f2bf_hw(e1);
    }
    if (kt == diagkt) {  // capture raw diagonal P (uniform branch, once per wave)
#pragma unroll
      for (int r = 0; r < 16; ++r) {
        const int myrow = (r & 3) + 8 * (r >> 2) + h4;
        float e = __builtin_amdgcn_exp2f((w & 1) ? sf1[r] : sf0[r]);
        if (l31 == myrow) diagP[w * 32 + myrow] = e;
      }
    }

    // PV: O[q 32][d 64] += P * V'  (pw rows wave-private; lgkm deps in-wave)
    short8 pa[4];
#pragma unroll
    for (int ks = 0; ks < 4; ++ks)
      pa[ks] = *reinterpret_cast<const short8*>(&pw[rdP[ks]]);
    __builtin_amdgcn_s_setprio(1);
#pragma unroll
    for (int dc = 0; dc < 2; ++dc)
#pragma unroll
      for (int ks = 0; ks < 4; ++ks) {
        short8 bv = *reinterpret_cast<const short8*>(&vT2[cur][rdV[dc][ks]]);
        oacc[dc] = __builtin_amdgcn_mfma_f32_32x32x16_bf16(pa[ks], bv, oacc[dc], 0, 0, 0);
      }
    __builtin_amdgcn_s_setprio(0);

    if (kt < 31) {
      const int nx = cur ^ 1;
      *reinterpret_cast<short8*>(&lK2[nx][wK0]) = pk0;
      *reinterpret_cast<short8*>(&lK2[nx][wK1]) = pk1;
      *reinterpret_cast<short8*>(&vT2[nx][wK0]) = pv0;
      *reinterpret_cast<short8*>(&vT2[nx][wK1]) = pv1;
    }
    __syncthreads();
  }

  // reduce lacc over the 32 k-columns (lanes l31; halves stay separate)
#pragma unroll
  for (int o = 1; o <= 16; o <<= 1)
#pragma unroll
    for (int r = 0; r < 16; ++r) lacc[r] += __shfl_xor(lacc[r], o, 64);

  const float rb = rsum[b];
#pragma unroll
  for (int r = 0; r < 16; ++r) {
    const int q = w * 32 + (r & 3) + 8 * (r >> 2) + h4;
    const int qg = qt * 128 + q;
    const float rq = reaches[b * S_ + qg];
    const float contrib = (rb - rq) / (rb + 1e-9f) * (1.f - rq) * 100.f;
    const float corr = 0.999999f * diagP[q] * rq;
    const float linv = 1.0f / lacc[r];
#pragma unroll
    for (int dc = 0; dc < 2; ++dc) {
      int d = dc * 32 + l31;
      float vhv = bf2f(Vh[base + (size_t)qg * DK_ + d]);
      float pv = (oacc[dc][r] - corr * vhv) * linv;
      float o = (vhv - pv) * contrib;
      concat[((size_t)(b * S_ + qg)) * D_ + h * 64 + d] = f2bf(o);
    }
  }
}

extern "C" void kernel_launch(void* const* d_in, const int* in_sizes, int n_in,
                              void* d_out, int out_size, void* d_ws, size_t ws_size,
                              hipStream_t stream) {
  const float* q = (const float*)d_in[0];
  const float* k = (const float*)d_in[1];
  const float* v = (const float*)d_in[2];
  const float* reaches = (const float*)d_in[3];
  const float* Wq = (const float*)d_in[4];
  const float* Wk = (const float*)d_in[5];
  const float* Wv = (const float*)d_in[6];
  const float* Wo = (const float*)d_in[7];

  const size_t NQKV = (size_t)B_ * S_ * D_;
  const size_t NW = (size_t)D_ * D_;

  us* q_bf = (us*)d_ws;
  us* k_bf = q_bf + NQKV;
  us* v_bf = k_bf + NQKV;
  us* Wq_bf = v_bf + NQKV;
  us* Wk_bf = Wq_bf + NW;
  us* Wv_bf = Wk_bf + NW;
  us* Wo_bf = Wv_bf + NW;
  us* Qh = Wo_bf + NW;
  us* Kh = Qh + NQKV;
  us* Vh = Kh + NQKV;
  us* concat = Vh + NQKV;
  float* rs = (float*)(concat + NQKV);
  us* VhTw = q_bf;  // alias: q_bf dead after proj_gemm

  cvt_all<<<16384, 256, 0, stream>>>(q, k, v, Wq, Wk, Wv, Wo,
                                     q_bf, k_bf, v_bf, Wq_bf, Wk_bf, Wv_bf, Wo_bf);
  rs_kernel<<<B_, 256, 0, stream>>>(reaches, rs);

  proj_gemm<<<dim3(256, 3), 256, 0, stream>>>(q_bf, k_bf, v_bf, Wq_bf, Wk_bf, Wv_bf, Qh, Kh, Vh);
  transp_kernel<<<B_ * H_ * (S_ / 64), 256, 0, stream>>>(Vh, reaches, VhTw);

  attn_kernel<<<B_ * H_ * (S_ / 128), 256, 0, stream>>>(Qh, Kh, Vh, VhTw, reaches, rs, concat);

  wo_gemm<<<512, 256, 0, stream>>>(concat, Wo_bf, (float*)d_out);
}

// Round 8
// 133.050 us; speedup vs baseline: 1.2976x; 1.0623x over previous
//
#include <hip/hip_runtime.h>
#include <hip/hip_bf16.h>

typedef __attribute__((ext_vector_type(8))) short short8;
typedef __attribute__((ext_vector_type(4))) float f32x4;
typedef __attribute__((ext_vector_type(16))) float f32x16;
typedef unsigned short us;

#define B_ 2
#define S_ 2048
#define D_ 1024
#define H_ 16
#define DK_ 64
#define QSCALE 0.1803368867f  // log2(e) / 8

__device__ __forceinline__ us f2bf(float f) {
  union { float f; unsigned u; } x; x.f = f;
  unsigned r = x.u + 0x7FFFu + ((x.u >> 16) & 1u);
  return (us)(r >> 16);
}
__device__ __forceinline__ float bf2f(us h) {
  union { unsigned u; float f; } x; x.u = ((unsigned)h) << 16;
  return x.f;
}
__device__ __forceinline__ us f2bf_hw(float f) {
  __hip_bfloat16 h = __float2bfloat16(f);
  return *reinterpret_cast<us*>(&h);
}
__device__ __forceinline__ unsigned cvtpk(float lo, float hi) {
  unsigned r;
  asm("v_cvt_pk_bf16_f32 %0, %1, %2" : "=v"(r) : "v"(lo), "v"(hi));
  return r;
}

__device__ __forceinline__ void gload16(const void* g, void* l) {
  __builtin_amdgcn_global_load_lds((const __attribute__((address_space(1))) void*)g,
                                   (__attribute__((address_space(3))) void*)l, 16, 0, 0);
}

// One kernel for all 7 fp32->bf16 conversions.
__global__ __launch_bounds__(256) void cvt_all(const float* __restrict__ q,
                                               const float* __restrict__ k,
                                               const float* __restrict__ v,
                                               const float* __restrict__ Wq,
                                               const float* __restrict__ Wk,
                                               const float* __restrict__ Wv,
                                               const float* __restrict__ Wo,
                                               us* __restrict__ oq, us* __restrict__ ok,
                                               us* __restrict__ ov, us* __restrict__ oWq,
                                               us* __restrict__ oWk, us* __restrict__ oWv,
                                               us* __restrict__ oWo) {
  int bid = blockIdx.x;
  const float* in; us* out; int off;
  if (bid < 12288) {
    int t = bid >> 12;
    in = (t == 0) ? q : (t == 1) ? k : v;
    out = (t == 0) ? oq : (t == 1) ? ok : ov;
    off = (bid & 4095) * 1024;
  } else {
    int t = (bid - 12288) >> 10;
    in = (t == 0) ? Wq : (t == 1) ? Wk : (t == 2) ? Wv : Wo;
    out = (t == 0) ? oWq : (t == 1) ? oWk : (t == 2) ? oWv : oWo;
    off = ((bid - 12288) & 1023) * 1024;
  }
  int i = off + threadIdx.x * 4;
  float4 val = *reinterpret_cast<const float4*>(in + i);
  ushort4 o;
  o.x = f2bf(val.x); o.y = f2bf(val.y); o.z = f2bf(val.z); o.w = f2bf(val.w);
  *reinterpret_cast<ushort4*>(out + i) = o;
}

__global__ __launch_bounds__(256) void rs_kernel(const float* __restrict__ reaches,
                                                 float* __restrict__ rs) {
  int b = blockIdx.x, t = threadIdx.x;
  float s = 0.f;
  for (int i = t; i < S_; i += 256) s += reaches[b * S_ + i];
  for (int o = 32; o > 0; o >>= 1) s += __shfl_down(s, o, 64);
  __shared__ float tmp[4];
  if ((t & 63) == 0) tmp[t >> 6] = s;
  __syncthreads();
  if (t == 0) rs[b] = tmp[0] + tmp[1] + tmp[2] + tmp[3];
}

// m97-structure GEMM: 128x128 tile, BK=32, linear LDS + global_load_lds w16.
__device__ __forceinline__ void gemm_core_hs(const us* __restrict__ A, const us* __restrict__ Bt,
                                             us* __restrict__ outH, float oscale) {
  __shared__ __align__(16) us lA[128 * 32];
  __shared__ __align__(16) us lB[128 * 32];
  const int tid = threadIdx.x;
  const int bm = blockIdx.x >> 3, bn = blockIdx.x & 7;
  const int w = tid >> 6, lane = tid & 63;
  const int wr = (w >> 1) * 64, wc = (w & 1) * 64;
  const int lr = lane & 15, lg = lane >> 4;

  f32x4 acc[4][4];
#pragma unroll
  for (int i = 0; i < 4; ++i)
#pragma unroll
    for (int j = 0; j < 4; ++j) acc[i][j] = (f32x4){0.f, 0.f, 0.f, 0.f};

  const int crow = lane >> 2, ce8 = (lane & 3) * 8;
  const us* A0 = A + (size_t)(bm * 128 + w * 32 + crow) * 1024 + ce8;
  const us* A1 = A0 + (size_t)16 * 1024;
  const us* B0 = Bt + (size_t)(bn * 128 + w * 32 + crow) * 1024 + ce8;
  const us* B1 = B0 + (size_t)16 * 1024;
  us* lA0 = &lA[(w * 2) * 512]; us* lA1 = lA0 + 512;
  us* lB0 = &lB[(w * 2) * 512]; us* lB1 = lB0 + 512;

  for (int kt = 0; kt < 1024; kt += 32) {
    gload16(A0 + kt, lA0);
    gload16(A1 + kt, lA1);
    gload16(B0 + kt, lB0);
    gload16(B1 + kt, lB1);
    __syncthreads();
    short8 af[4], bfr[4];
#pragma unroll
    for (int i = 0; i < 4; ++i)
      af[i] = *reinterpret_cast<const short8*>(&lA[(wr + i * 16 + lr) * 32 + lg * 8]);
#pragma unroll
    for (int j = 0; j < 4; ++j)
      bfr[j] = *reinterpret_cast<const short8*>(&lB[(wc + j * 16 + lr) * 32 + lg * 8]);
#pragma unroll
    for (int i = 0; i < 4; ++i)
#pragma unroll
      for (int j = 0; j < 4; ++j)
        acc[i][j] = __builtin_amdgcn_mfma_f32_16x16x32_bf16(af[i], bfr[j], acc[i][j], 0, 0, 0);
    __syncthreads();
  }
#pragma unroll
  for (int i = 0; i < 4; ++i)
#pragma unroll
    for (int j = 0; j < 4; ++j)
#pragma unroll
      for (int ii = 0; ii < 4; ++ii) {
        int r = bm * 128 + wr + i * 16 + lg * 4 + ii;
        int c = bn * 128 + wc + j * 16 + lr;
        float v = acc[i][j][ii] * oscale;
        int b = r >> 11, s = r & (S_ - 1), h = c >> 6, dk = c & 63;
        outH[(((size_t)(b * H_ + h) * S_ + s) * DK_) + dk] = f2bf(v);
      }
}

__global__ __launch_bounds__(256) void proj_gemm(const us* __restrict__ q_bf,
                                                 const us* __restrict__ k_bf,
                                                 const us* __restrict__ v_bf,
                                                 const us* __restrict__ Wq_bf,
                                                 const us* __restrict__ Wk_bf,
                                                 const us* __restrict__ Wv_bf,
                                                 us* __restrict__ Qh, us* __restrict__ Kh,
                                                 us* __restrict__ Vh) {
  if (blockIdx.y == 0) gemm_core_hs(q_bf, Wq_bf, Qh, QSCALE);
  else if (blockIdx.y == 1) gemm_core_hs(k_bf, Wk_bf, Kh, 1.0f);
  else gemm_core_hs(v_bf, Wv_bf, Vh, 1.0f);
}

// Wo GEMM: 128x64 tile (grid 512 = 2 blocks/CU), fp32 output.
__global__ __launch_bounds__(256) void wo_gemm(const us* __restrict__ A,
                                               const us* __restrict__ Bt,
                                               float* __restrict__ outF) {
  __shared__ __align__(16) us lA[128 * 32];
  __shared__ __align__(16) us lB[64 * 32];
  const int tid = threadIdx.x;
  const int bm = blockIdx.x >> 4, bn = blockIdx.x & 15;
  const int w = tid >> 6, lane = tid & 63;
  const int lr = lane & 15, lg = lane >> 4;

  f32x4 acc[2][4];
#pragma unroll
  for (int i = 0; i < 2; ++i)
#pragma unroll
    for (int j = 0; j < 4; ++j) acc[i][j] = (f32x4){0.f, 0.f, 0.f, 0.f};

  const int crow = lane >> 2, ce8 = (lane & 3) * 8;
  const us* A0 = A + (size_t)(bm * 128 + w * 32 + crow) * 1024 + ce8;
  const us* A1 = A0 + (size_t)16 * 1024;
  const us* B0 = Bt + (size_t)(bn * 64 + w * 16 + crow) * 1024 + ce8;
  us* lA0 = &lA[w * 1024]; us* lA1 = lA0 + 512;
  us* lB0 = &lB[w * 512];

  for (int kt = 0; kt < 1024; kt += 32) {
    gload16(A0 + kt, lA0);
    gload16(A1 + kt, lA1);
    gload16(B0 + kt, lB0);
    __syncthreads();
    short8 af[2], bfr[4];
#pragma unroll
    for (int i = 0; i < 2; ++i)
      af[i] = *reinterpret_cast<const short8*>(&lA[(w * 32 + i * 16 + lr) * 32 + lg * 8]);
#pragma unroll
    for (int j = 0; j < 4; ++j)
      bfr[j] = *reinterpret_cast<const short8*>(&lB[(j * 16 + lr) * 32 + lg * 8]);
#pragma unroll
    for (int i = 0; i < 2; ++i)
#pragma unroll
      for (int j = 0; j < 4; ++j)
        acc[i][j] = __builtin_amdgcn_mfma_f32_16x16x32_bf16(af[i], bfr[j], acc[i][j], 0, 0, 0);
    __syncthreads();
  }
#pragma unroll
  for (int i = 0; i < 2; ++i)
#pragma unroll
    for (int j = 0; j < 4; ++j)
#pragma unroll
      for (int ii = 0; ii < 4; ++ii) {
        int r = bm * 128 + w * 32 + i * 16 + lg * 4 + ii;
        int c = bn * 64 + j * 16 + lr;
        outF[(size_t)r * 1024 + c] = acc[i][j][ii];
      }
}

// Vh [B,H,S,DK] -> VhTw [B,H,DK,S] with reach weighting folded in.
__global__ __launch_bounds__(256) void transp_kernel(const us* __restrict__ Vh,
                                                     const float* __restrict__ reaches,
                                                     us* __restrict__ VhTw) {
  __shared__ us t[64 * 68];
  const int bh = blockIdx.x >> 5, st = blockIdx.x & 31;
  const int b = bh >> 4;
  const size_t base = (size_t)bh * S_ * DK_;
  const int r = threadIdx.x >> 3, e8 = (threadIdx.x & 7) * 8;
#pragma unroll
  for (int h2 = 0; h2 < 2; ++h2) {
    int row = r + h2 * 32;
    *reinterpret_cast<short8*>(&t[row * 68 + e8]) =
        *reinterpret_cast<const short8*>(&Vh[base + (size_t)(st * 64 + row) * DK_ + e8]);
  }
  __syncthreads();
#pragma unroll
  for (int h2 = 0; h2 < 2; ++h2) {
    int dk = (threadIdx.x >> 3) + h2 * 32;
    int sc = (threadIdx.x & 7) * 8;
    short8 v;
#pragma unroll
    for (int j = 0; j < 8; ++j) {
      float rw = reaches[b * S_ + st * 64 + sc + j];
      v[j] = (short)f2bf_hw(bf2f(t[(sc + j) * 68 + dk]) * rw);
    }
    *reinterpret_cast<short8*>(&VhTw[base + (size_t)dk * S_ + st * 64 + sc]) = v;
  }
}

// 32x32-MFMA streaming-softmax attention, swapped QK^T + in-register P (T12).
// 4 waves x 32 q-rows; Q in regs (as B-operand); K/V' dbuf swizzled LDS; 1 barrier/kt.
__global__ __launch_bounds__(256, 2) void attn_kernel(const us* __restrict__ Qh,
                                                      const us* __restrict__ Kh,
                                                      const us* __restrict__ Vh,
                                                      const us* __restrict__ VhTw,
                                                      const float* __restrict__ reaches,
                                                      const float* __restrict__ rsum,
                                                      us* __restrict__ concat) {
  __shared__ __align__(16) us lK2[2][64 * 64];
  __shared__ __align__(16) us vT2[2][64 * 64];
  __shared__ float diagP[128];
  __shared__ float lsum[128];

  const int tid = threadIdx.x;
  const int bid = ((blockIdx.x & 7) << 6) | (blockIdx.x >> 3);  // XCD swizzle (512 = 8*64)
  const int qt = bid & 15;
  const int bh = bid >> 4;
  const int b = bh >> 4, h = bh & 15;
  const size_t base = (size_t)bh * S_ * DK_;

  const int w = tid >> 6, lane = tid & 63;
  const int l31 = lane & 31, hh = lane >> 5, l7 = lane & 7;
  const int h4 = hh * 4;
  const int r2 = tid >> 3, e8 = (tid & 7) * 8;
  const int diagkt = qt * 2 + (w >> 1);

  // Q fragments (B-operand for swapped QK; A-operand layout == B layout per lane)
  short8 aq[4];
  {
    const us* qp = &Qh[base + (size_t)(qt * 128 + w * 32 + l31) * DK_ + hh * 8];
#pragma unroll
    for (int dk = 0; dk < 4; ++dk)
      aq[dk] = *reinterpret_cast<const short8*>(qp + dk * 16);
  }

  // loop-invariant LDS element offsets (XOR swizzle at 16B granularity)
  int rdK[2][4];
#pragma unroll
  for (int c = 0; c < 2; ++c)
#pragma unroll
    for (int dk = 0; dk < 4; ++dk)
      rdK[c][dk] = (c * 32 + l31) * 64 + (((dk * 2 + hh) ^ l7) << 3);
  const int wslot = ((tid & 7) ^ (r2 & 7)) << 3;
  const int wK0 = r2 * 64 + wslot, wK1 = (r2 + 32) * 64 + wslot;

  // prologue: stage tile 0
  short8 pk0, pk1, pv0, pv1;
  pk0 = *reinterpret_cast<const short8*>(&Kh[base + (size_t)r2 * DK_ + e8]);
  pk1 = *reinterpret_cast<const short8*>(&Kh[base + (size_t)(r2 + 32) * DK_ + e8]);
  pv0 = *reinterpret_cast<const short8*>(&VhTw[base + (size_t)r2 * S_ + e8]);
  pv1 = *reinterpret_cast<const short8*>(&VhTw[base + (size_t)(r2 + 32) * S_ + e8]);
  *reinterpret_cast<short8*>(&lK2[0][wK0]) = pk0;
  *reinterpret_cast<short8*>(&lK2[0][wK1]) = pk1;
  *reinterpret_cast<short8*>(&vT2[0][wK0]) = pv0;
  *reinterpret_cast<short8*>(&vT2[0][wK1]) = pv1;
  __syncthreads();

  f32x16 oacc[2];
  float lacc = 0.f;
#pragma unroll
  for (int c = 0; c < 2; ++c)
#pragma unroll
    for (int r = 0; r < 16; ++r) oacc[c][r] = 0.f;

  for (int kt = 0; kt < 32; ++kt) {
    const int cur = kt & 1;
    if (kt < 31) {
      int nt = kt + 1;
      pk0 = *reinterpret_cast<const short8*>(&Kh[base + (size_t)(nt * 64 + r2) * DK_ + e8]);
      pk1 = *reinterpret_cast<const short8*>(&Kh[base + (size_t)(nt * 64 + r2 + 32) * DK_ + e8]);
      pv0 = *reinterpret_cast<const short8*>(&VhTw[base + (size_t)r2 * S_ + nt * 64 + e8]);
      pv1 = *reinterpret_cast<const short8*>(&VhTw[base + (size_t)(r2 + 32) * S_ + nt * 64 + e8]);
    }

    // swapped QK^T: st_c[k=crow][q=l31] = mfma(A=K chunk c, B=Q)
    f32x16 st0, st1;
#pragma unroll
    for (int r = 0; r < 16; ++r) { st0[r] = 0.f; st1[r] = 0.f; }
    __builtin_amdgcn_s_setprio(1);
#pragma unroll
    for (int dk = 0; dk < 4; ++dk) {
      short8 k0 = *reinterpret_cast<const short8*>(&lK2[cur][rdK[0][dk]]);
      st0 = __builtin_amdgcn_mfma_f32_32x32x16_bf16(k0, aq[dk], st0, 0, 0, 0);
      short8 k1 = *reinterpret_cast<const short8*>(&lK2[cur][rdK[1][dk]]);
      st1 = __builtin_amdgcn_mfma_f32_32x32x16_bf16(k1, aq[dk], st1, 0, 0, 0);
    }
    __builtin_amdgcn_s_setprio(0);

    // streaming softmax fully in-register: e = 2^st, per-lane partial l
    float e0[16], e1[16];
#pragma unroll
    for (int r = 0; r < 16; ++r) {
      e0[r] = __builtin_amdgcn_exp2f(st0[r]);
      e1[r] = __builtin_amdgcn_exp2f(st1[r]);
      lacc += e0[r] + e1[r];
    }
    if (kt == diagkt) {  // raw diagonal P for epilogue correction
#pragma unroll
      for (int r = 0; r < 16; ++r) {
        int kk = (r & 3) + 8 * (r >> 2) + 4 * hh;
        float ev = (w & 1) ? e1[r] : e0[r];
        if (kk == l31) diagP[w * 32 + l31] = ev;
      }
    }

    // P -> bf16 A-frags via cvt_pk + permlane32_swap (no LDS round-trip)
    short8 pa[4];
#pragma unroll
    for (int ks = 0; ks < 4; ++ks) {
      const int ro = (ks & 1) * 8;
      unsigned d0, s0, d1, s1;
      if (ks < 2) {
        d0 = cvtpk(e0[ro + 0], e0[ro + 1]);
        s0 = cvtpk(e0[ro + 4], e0[ro + 5]);
        d1 = cvtpk(e0[ro + 2], e0[ro + 3]);
        s1 = cvtpk(e0[ro + 6], e0[ro + 7]);
      } else {
        d0 = cvtpk(e1[ro + 0], e1[ro + 1]);
        s0 = cvtpk(e1[ro + 4], e1[ro + 5]);
        d1 = cvtpk(e1[ro + 2], e1[ro + 3]);
        s1 = cvtpk(e1[ro + 6], e1[ro + 7]);
      }
      asm("v_permlane32_swap_b32 %0, %1" : "+v"(d0), "+v"(s0));
      asm("v_permlane32_swap_b32 %0, %1" : "+v"(d1), "+v"(s1));
      union { unsigned u[4]; short8 v; } pk;
      pk.u[0] = d0; pk.u[1] = d1; pk.u[2] = s0; pk.u[3] = s1;
      pa[ks] = pk.v;
    }

    // PV: O[q][d] += P * V'
    __builtin_amdgcn_s_setprio(1);
#pragma unroll
    for (int dc = 0; dc < 2; ++dc)
#pragma unroll
      for (int ks = 0; ks < 4; ++ks) {
        short8 bv = *reinterpret_cast<const short8*>(&vT2[cur][rdK[dc][ks]]);
        oacc[dc] = __builtin_amdgcn_mfma_f32_32x32x16_bf16(pa[ks], bv, oacc[dc], 0, 0, 0);
      }
    __builtin_amdgcn_s_setprio(0);

    if (kt < 31) {
      const int nx = cur ^ 1;
      *reinterpret_cast<short8*>(&lK2[nx][wK0]) = pk0;
      *reinterpret_cast<short8*>(&lK2[nx][wK1]) = pk1;
      *reinterpret_cast<short8*>(&vT2[nx][wK0]) = pv0;
      *reinterpret_cast<short8*>(&vT2[nx][wK1]) = pv1;
    }
    __syncthreads();
  }

  // total l per q: merge the two hh halves, broadcast via LDS
  lacc += __shfl_xor(lacc, 32, 64);
  if (hh == 0) lsum[w * 32 + l31] = lacc;
  __syncthreads();

  const float rb = rsum[b];
#pragma unroll
  for (int r = 0; r < 16; ++r) {
    const int q = w * 32 + (r & 3) + 8 * (r >> 2) + h4;
    const int qg = qt * 128 + q;
    const float rq = reaches[b * S_ + qg];
    const float contrib = (rb - rq) / (rb + 1e-9f) * (1.f - rq) * 100.f;
    const float corr = 0.999999f * diagP[q] * rq;
    const float linv = 1.0f / lsum[q];
#pragma unroll
    for (int dc = 0; dc < 2; ++dc) {
      int d = dc * 32 + l31;
      float vhv = bf2f(Vh[base + (size_t)qg * DK_ + d]);
      float pv = (oacc[dc][r] - corr * vhv) * linv;
      float o = (vhv - pv) * contrib;
      concat[((size_t)(b * S_ + qg)) * D_ + h * 64 + d] = f2bf(o);
    }
  }
}

extern "C" void kernel_launch(void* const* d_in, const int* in_sizes, int n_in,
                              void* d_out, int out_size, void* d_ws, size_t ws_size,
                              hipStream_t stream) {
  const float* q = (const float*)d_in[0];
  const float* k = (const float*)d_in[1];
  const float* v = (const float*)d_in[2];
  const float* reaches = (const float*)d_in[3];
  const float* Wq = (const float*)d_in[4];
  const float* Wk = (const float*)d_in[5];
  const float* Wv = (const float*)d_in[6];
  const float* Wo = (const float*)d_in[7];

  const size_t NQKV = (size_t)B_ * S_ * D_;
  const size_t NW = (size_t)D_ * D_;

  us* q_bf = (us*)d_ws;
  us* k_bf = q_bf + NQKV;
  us* v_bf = k_bf + NQKV;
  us* Wq_bf = v_bf + NQKV;
  us* Wk_bf = Wq_bf + NW;
  us* Wv_bf = Wk_bf + NW;
  us* Wo_bf = Wv_bf + NW;
  us* Qh = Wo_bf + NW;
  us* Kh = Qh + NQKV;
  us* Vh = Kh + NQKV;
  us* concat = Vh + NQKV;
  float* rs = (float*)(concat + NQKV);
  us* VhTw = q_bf;  // alias: q_bf dead after proj_gemm

  cvt_all<<<16384, 256, 0, stream>>>(q, k, v, Wq, Wk, Wv, Wo,
                                     q_bf, k_bf, v_bf, Wq_bf, Wk_bf, Wv_bf, Wo_bf);
  rs_kernel<<<B_, 256, 0, stream>>>(reaches, rs);

  proj_gemm<<<dim3(256, 3), 256, 0, stream>>>(q_bf, k_bf, v_bf, Wq_bf, Wk_bf, Wv_bf, Qh, Kh, Vh);
  transp_kernel<<<B_ * H_ * (S_ / 64), 256, 0, stream>>>(Vh, reaches, VhTw);

  attn_kernel<<<B_ * H_ * (S_ / 128), 256, 0, stream>>>(Qh, Kh, Vh, VhTw, reaches, rs, concat);

  wo_gemm<<<512, 256, 0, stream>>>(concat, Wo_bf, (float*)d_out);
}